// Round 21
// baseline (12416.239 us; speedup 1.0000x reference)
//
#include <hip/hip_runtime.h>
#include <math.h>

typedef __attribute__((ext_vector_type(8))) short short8;
typedef __attribute__((ext_vector_type(8))) unsigned short u16x8;
typedef __attribute__((ext_vector_type(4))) float f32x4;
typedef __attribute__((ext_vector_type(2))) float f32x2;
typedef long i64;

#define USER_NUM_  100000
#define COMP_NUM_  50000
#define EN         150002
#define REL_NUM_   200
#define DD         128
#define TT         12
#define EE         250000
#define SS         20000
#define BB         1024
#define PPART      125      // comp partitions
#define TILES_PP   25       // 16-comp tiles per partition
#define NB         37       // coarse buckets: dst>>12, 37*4096 >= EN
#define BSH        12
#define CHUNK      4096     // edges per binA/binB block
#define NCH        62       // ceil(EE/CHUNK)
#define XHROW      512      // xh row bytes: [x fp8 128 | h_old fp8 128 | c_old bf16 256]
#define GAGG       ((EN + 15) / 16)   // 9376 agg blocks
#define GLSTM      (SS / 32)          // 625 lstm blocks

__device__ inline unsigned short f2bf(float f) {
    unsigned u = __float_as_uint(f);
    unsigned r = (u + 0x7fffu + ((u >> 16) & 1u)) >> 16;
    return (unsigned short)r;
}

__device__ inline float bf2f(unsigned short u) {
    return __uint_as_float((unsigned)u << 16);
}

// ---- fp8 e4m3 (OCP) hardware converts ----
__device__ inline void fp8x8_to_f(uint2 u, float f[8]) {
    f32x2 a = __builtin_amdgcn_cvt_pk_f32_fp8((int)u.x, false);
    f32x2 b = __builtin_amdgcn_cvt_pk_f32_fp8((int)u.x, true);
    f32x2 c = __builtin_amdgcn_cvt_pk_f32_fp8((int)u.y, false);
    f32x2 d = __builtin_amdgcn_cvt_pk_f32_fp8((int)u.y, true);
    f[0] = a[0]; f[1] = a[1]; f[2] = b[0]; f[3] = b[1];
    f[4] = c[0]; f[5] = c[1]; f[6] = d[0]; f[7] = d[1];
}

__device__ inline unsigned fp8x4_pack(float f0, float f1, float f2, float f3) {
    int v = __builtin_amdgcn_cvt_pk_fp8_f32(f0, f1, 0, false);
    v = __builtin_amdgcn_cvt_pk_fp8_f32(f2, f3, v, true);
    return (unsigned)v;
}

__device__ inline unsigned char f_to_fp8(float f) {
    return (unsigned char)(__builtin_amdgcn_cvt_pk_fp8_f32(f, f, 0, false) & 0xff);
}

__device__ inline float fp8_to_f(unsigned char b) {
    return __builtin_amdgcn_cvt_f32_fp8((int)b, 0);
}

__device__ inline float sigmoidf_(float x) { return 1.f / (1.f + __expf(-x)); }

__device__ inline void lse_push(float v, float& m, float& s) {
    if (v <= m) { s += __expf(v - m); }
    else { s = s * __expf(m - v) + 1.f; m = v; }
}

__device__ inline void lse_merge(float& M, float& S, float M2, float S2) {
    float Mn = fmaxf(M, M2);
    S = S * __expf(M - Mn) + S2 * __expf(M2 - Mn);
    M = Mn;
}

// ---------------- utility ----------------
__global__ __launch_bounds__(256) void packBF_k(const float* __restrict__ src, ushort4* __restrict__ dst, int n4) {
    int i = blockIdx.x * 256 + threadIdx.x;
    if (i >= n4) return;
    float4 v = ((const float4*)src)[i];
    ushort4 o;
    o.x = f2bf(v.x); o.y = f2bf(v.y); o.z = f2bf(v.z); o.w = f2bf(v.w);
    dst[i] = o;
}

__global__ __launch_bounds__(256) void packF8_k(const float* __restrict__ src, unsigned* __restrict__ dst, int n4) {
    int i = blockIdx.x * 256 + threadIdx.x;
    if (i >= n4) return;
    float4 v = ((const float4*)src)[i];
    dst[i] = fp8x4_pack(v.x, v.y, v.z, v.w);
}

__global__ __launch_bounds__(256) void zero_i32_k(int* __restrict__ p, int n) {
    int i = blockIdx.x * 256 + threadIdx.x;
    if (i < n) p[i] = 0;
}

// W packed to fp8: Wt8[n][k], n=gate unit (512), k=0..255 ([xi|hp] order)
__global__ __launch_bounds__(256) void prepW_k(const float* __restrict__ Wih, const float* __restrict__ Whh,
                                               const float* __restrict__ bih, const float* __restrict__ bhh,
                                               unsigned char* __restrict__ Wt8, float* __restrict__ bsum) {
    int n = blockIdx.x;      // 0..511
    int k = threadIdx.x;     // 0..255
    float v = (k < 128) ? Wih[n * 128 + k] : Whh[n * 128 + (k - 128)];
    Wt8[n * 256 + k] = f_to_fp8(v);
    if (k == 0) bsum[n] = bih[n] + bhh[n];
}

// seedpos[slot][d] = index of d in seed list (or -1, via memset 0xFF)
__global__ __launch_bounds__(256) void spos_k(const int* __restrict__ seed, int* __restrict__ seedpos,
                                              int t0) {
    int slot = blockIdx.y;
    int i = blockIdx.x * 256 + threadIdx.x;
    if (i < SS) seedpos[(size_t)slot * EN + seed[(size_t)(t0 + slot) * SS + i]] = i;
}

// ---------------- two-level binned CSR build ----------------
__global__ __launch_bounds__(256) void binA_k(const int* __restrict__ dst, int* __restrict__ bcnt,
                                              int t0) {
    int slot = blockIdx.y;
    int tid = threadIdx.x;
    int c0 = blockIdx.x * CHUNK;
    int w = tid >> 6;
    __shared__ int lcnt[4][NB];
    for (int i = tid; i < 4 * NB; i += 256) ((int*)lcnt)[i] = 0;
    __syncthreads();
#pragma unroll
    for (int i = 0; i < 16; ++i) {
        int e = c0 + i * 256 + tid;
        if (e < EE) {
            int d = __builtin_nontemporal_load(&dst[(size_t)(t0 + slot) * EE + e]);
            atomicAdd(&lcnt[w][d >> BSH], 1);
        }
    }
    __syncthreads();
    if (tid < NB)
        atomicAdd(&bcnt[slot * NB + tid], lcnt[0][tid] + lcnt[1][tid] + lcnt[2][tid] + lcnt[3][tid]);
}

__global__ __launch_bounds__(64) void binScan_k(const int* __restrict__ bcnt, int* __restrict__ bbase,
                                                int* __restrict__ bcur, int nt) {
    int slot = threadIdx.x;
    if (slot >= nt) return;
    int b = 0;
    for (int c = 0; c < NB; ++c) {
        bbase[slot * (NB + 1) + c] = b;
        bcur[slot * NB + c] = b;
        b += bcnt[slot * NB + c];
    }
    bbase[slot * (NB + 1) + NB] = b;   // == EE
}

__global__ __launch_bounds__(256) void binB_k(const int* __restrict__ src, const int* __restrict__ dst,
                                              const int* __restrict__ rel, int* __restrict__ bcur,
                                              int2* __restrict__ bucketed, int t0) {
    int slot = blockIdx.y;
    int tid = threadIdx.x;
    int c0 = blockIdx.x * CHUNK;
    __shared__ int lcnt[NB], lbase[NB], gbase[NB], lcur[NB];
    __shared__ int2 stage[CHUNK];   // 32 KB
    if (tid < NB) lcnt[tid] = 0;
    __syncthreads();

    int myb[16]; int2 myv[16];
#pragma unroll
    for (int i = 0; i < 16; ++i) {
        int e = c0 + i * 256 + tid;
        if (e < EE) {
            size_t gi = (size_t)(t0 + slot) * EE + e;
            int d = __builtin_nontemporal_load(&dst[gi]);
            int s = __builtin_nontemporal_load(&src[gi]);
            int r = __builtin_nontemporal_load(&rel[gi]);
            myb[i] = d >> BSH;
            myv[i] = make_int2(d, s | (r << 18));
            atomicAdd(&lcnt[myb[i]], 1);
        } else myb[i] = -1;
    }
    __syncthreads();
    if (tid == 0) {
        int b = 0;
        for (int c = 0; c < NB; ++c) { lbase[c] = b; b += lcnt[c]; }
    }
    __syncthreads();
    if (tid < NB) {
        gbase[tid] = (lcnt[tid] > 0) ? atomicAdd(&bcur[slot * NB + tid], lcnt[tid]) : 0;
        lcur[tid] = lbase[tid];
    }
    __syncthreads();
#pragma unroll
    for (int i = 0; i < 16; ++i) {
        if (myb[i] >= 0) {
            int p = atomicAdd(&lcur[myb[i]], 1);
            stage[p] = myv[i];
        }
    }
    __syncthreads();
    int w = tid >> 6, lane = tid & 63;
    int2* bout = bucketed + (size_t)slot * EE;
    for (int b = w; b < NB; b += 4) {
        int cnt = lcnt[b], lb = lbase[b], gb = gbase[b];
        for (int j = lane; j < cnt; j += 64)
            bout[gb + j] = stage[lb + j];
    }
}

// per-(slot,bucket): fused histogram + in-LDS scan + scatter + end-offset writeback.
__global__ __launch_bounds__(256) void histscat_k(const int2* __restrict__ bucketed,
                                                  const int* __restrict__ bbase,
                                                  int* __restrict__ startp, int* __restrict__ pairs) {
    int b = blockIdx.x, slot = blockIdx.y;
    int tid = threadIdx.x;
    int base_ent = b << BSH;
    int nloc = EN - base_ent; if (nloc > 4096) nloc = 4096;
    __shared__ int lcnt[4096];
    __shared__ int tsum[256];
    for (int i = tid; i < 4096; i += 256) lcnt[i] = 0;
    __syncthreads();
    int e0 = bbase[slot * (NB + 1) + b], e1 = bbase[slot * (NB + 1) + b + 1];
    const int2* bin = bucketed + (size_t)slot * EE;
    for (int e = e0 + tid; e < e1; e += 256)
        atomicAdd(&lcnt[bin[e].x - base_ent], 1);
    __syncthreads();
    int base16 = tid * 16;
    int s = 0;
#pragma unroll
    for (int k = 0; k < 16; ++k) s += lcnt[base16 + k];
    tsum[tid] = s;
    __syncthreads();
#pragma unroll
    for (int o = 1; o < 256; o <<= 1) {
        int x = (tid >= o) ? tsum[tid - o] : 0;
        __syncthreads();
        tsum[tid] += x;
        __syncthreads();
    }
    int run = e0 + tsum[tid] - s;
#pragma unroll
    for (int k = 0; k < 16; ++k) {
        int c = lcnt[base16 + k];
        lcnt[base16 + k] = run;
        run += c;
    }
    __syncthreads();
    int* pout = pairs + (size_t)slot * EE;
    for (int e = e0 + tid; e < e1; e += 256) {
        int2 ed = bin[e];
        int pos = atomicAdd(&lcnt[ed.x - base_ent], 1);
        pout[pos] = ed.y;
    }
    __syncthreads();
    for (int i = tid; i < nloc; i += 256)
        startp[(size_t)slot * EN + base_ent + i] = lcnt[i];   // end offsets
}

// ---------------- FUSED agg + lstm (device-scope barrier) ----------------
// Blocks [0, GAGG): aggregate + seed packing, then release ctr.
// Blocks [GAGG, GAGG+GLSTM): spin-acquire on ctr, then LSTM on packed xh.
__global__ __launch_bounds__(256, 3) void aggstm_k(const unsigned char* __restrict__ hold,
                                                   unsigned char* __restrict__ hnew,
                                                   const unsigned short* __restrict__ Rbf,
                                                   unsigned short* __restrict__ cbuf,
                                                   const int* __restrict__ endp_all,
                                                   const int* __restrict__ pairs,
                                                   const int* __restrict__ seedpos_all,
                                                   unsigned char* __restrict__ xh,
                                                   const unsigned char* __restrict__ Wt8,
                                                   const float* __restrict__ bsum,
                                                   const int* __restrict__ seed,
                                                   int* __restrict__ ctr, int slot) {
    int tid = threadIdx.x;
    if (blockIdx.x < GAGG) {
        // ================= agg part =================
        int d = blockIdx.x * 16 + (tid >> 4);
        int l = tid & 15;
        if (d < EN) {
            const int* endp = endp_all + (size_t)slot * EN;
            int e0 = (d > 0) ? endp[d - 1] : 0;
            int e1 = endp[d];
            const int* pp = pairs + (size_t)slot * EE;
            float acc[8];
#pragma unroll
            for (int j = 0; j < 8; ++j) acc[j] = 0.f;
            int e = e0;
            for (; e + 2 <= e1; e += 2) {
                int pk0 = pp[e], pk1 = pp[e + 1];
                uint2 h0 = *(const uint2*)(hold + (size_t)(pk0 & 0x3FFFF) * DD + l * 8);
                u16x8 r0 = *(const u16x8*)(Rbf + (size_t)(pk0 >> 18) * DD + l * 8);
                uint2 h1 = *(const uint2*)(hold + (size_t)(pk1 & 0x3FFFF) * DD + l * 8);
                u16x8 r1 = *(const u16x8*)(Rbf + (size_t)(pk1 >> 18) * DD + l * 8);
                float hf0[8], hf1[8];
                fp8x8_to_f(h0, hf0);
                fp8x8_to_f(h1, hf1);
#pragma unroll
                for (int j = 0; j < 8; ++j)
                    acc[j] = fmaf(hf1[j], bf2f(r1[j]), fmaf(hf0[j], bf2f(r0[j]), acc[j]));
            }
            if (e < e1) {
                int pk0 = pp[e];
                uint2 h0 = *(const uint2*)(hold + (size_t)(pk0 & 0x3FFFF) * DD + l * 8);
                u16x8 r0 = *(const u16x8*)(Rbf + (size_t)(pk0 >> 18) * DD + l * 8);
                float hf0[8];
                fp8x8_to_f(h0, hf0);
#pragma unroll
                for (int j = 0; j < 8; ++j)
                    acc[j] = fmaf(hf0[j], bf2f(r0[j]), acc[j]);
            }
            uint2 hd = *(const uint2*)(hold + (size_t)d * DD + l * 8);
            float hdf[8];
            fp8x8_to_f(hd, hdf);
            int c = e1 - e0;
            float inv = (c > 0) ? 1.f / (float)c : 0.f;
            float o[8];
#pragma unroll
            for (int j = 0; j < 8; ++j) o[j] = fmaf(acc[j], inv, hdf[j]);
            uint2 ov;
            ov.x = fp8x4_pack(o[0], o[1], o[2], o[3]);
            ov.y = fp8x4_pack(o[4], o[5], o[6], o[7]);
            *(uint2*)(hnew + (size_t)d * DD + l * 8) = ov;

            int sp = seedpos_all[(size_t)slot * EN + d];
            if (sp >= 0) {
                unsigned char* row = xh + (size_t)sp * XHROW;
                *(uint2*)(row + l * 8) = ov;          // x half (fp8)
                *(uint2*)(row + 128 + l * 8) = hd;    // h_old half (fp8)
                uint4 cv = *(const uint4*)(cbuf + (size_t)d * DD + l * 8);
                *(uint4*)(row + 256 + l * 16) = cv;   // c_old (bf16)
            }
        }
        __threadfence();                 // release: drain writes to device scope
        __syncthreads();
        if (tid == 0) atomicAdd(ctr, 1);
        return;
    }

    // ================= lstm part =================
    int m0 = (int)(blockIdx.x - GAGG) * 32;
    int w = tid >> 6;
    int lane = tid & 63;
    int lrow = lane & 15, lhi = lane >> 4;
    int w32 = w * 32;

    if (tid == 0) {
        while (__hip_atomic_load(ctr, __ATOMIC_ACQUIRE, __HIP_MEMORY_SCOPE_AGENT) < GAGG)
            __builtin_amdgcn_s_sleep(8);
    }
    __syncthreads();
    __threadfence();                     // acquire: invalidate stale cached lines

    f32x4 acc[2][4][2];
#pragma unroll
    for (int mi = 0; mi < 2; ++mi)
#pragma unroll
        for (int g = 0; g < 4; ++g)
#pragma unroll
            for (int s = 0; s < 2; ++s)
                acc[mi][g][s] = (f32x4){0.f, 0.f, 0.f, 0.f};

#pragma unroll
    for (int kk = 0; kk < 8; ++kk) {
        int klane = kk * 32 + lhi * 8;
        i64 af0 = *(const i64*)(xh + (size_t)(m0 + lrow) * XHROW + klane);
        i64 af1 = *(const i64*)(xh + (size_t)(m0 + 16 + lrow) * XHROW + klane);
#pragma unroll
        for (int g = 0; g < 4; ++g)
#pragma unroll
            for (int s = 0; s < 2; ++s) {
                int col = g * 128 + w32 + s * 16 + lrow;
                i64 bf = *(const i64*)(Wt8 + (size_t)col * 256 + klane);
                acc[0][g][s] = __builtin_amdgcn_mfma_f32_16x16x32_fp8_fp8(af0, bf, acc[0][g][s], 0, 0, 0);
                acc[1][g][s] = __builtin_amdgcn_mfma_f32_16x16x32_fp8_fp8(af1, bf, acc[1][g][s], 0, 0, 0);
            }
    }

#pragma unroll
    for (int mi = 0; mi < 2; ++mi) {
#pragma unroll
        for (int r = 0; r < 4; ++r) {
            int m = m0 + mi * 16 + lhi * 4 + r;
            int sd = seed[m];
#pragma unroll
            for (int s = 0; s < 2; ++s) {
                int d = w32 + s * 16 + lrow;
                float ig = acc[mi][0][s][r] + bsum[d];
                float fg = acc[mi][1][s][r] + bsum[128 + d];
                float gg = acc[mi][2][s][r] + bsum[256 + d];
                float og = acc[mi][3][s][r] + bsum[384 + d];
                float cp = bf2f(*(const unsigned short*)(xh + (size_t)m * XHROW + 256 + d * 2));
                float cn = sigmoidf_(fg) * cp + sigmoidf_(ig) * tanhf(gg);
                float hn = sigmoidf_(og) * tanhf(cn);
                cbuf[(size_t)sd * DD + d] = f2bf(cn);
                hnew[(size_t)sd * DD + d] = f_to_fp8(hn);
            }
        }
    }
}

// ---------------- comp loss: pack u rows (fp8 -> bf16) ----------------
__global__ __launch_bounds__(256) void packU_k(const unsigned char* __restrict__ hfin, const int* __restrict__ ub,
                                               short* __restrict__ Ubf) {
    int i = blockIdx.x * 256 + threadIdx.x;    // over 1024*128
    if (i >= BB * DD) return;
    int u = i >> 7, k = i & 127;
    Ubf[i] = (short)f2bf(fp8_to_f(hfin[(size_t)ub[u] * DD + k]));
}

// ---------------- comp loss: MFMA GEMM, LDS-staged tiles, no-max exp-sum ----------------
__global__ __launch_bounds__(256) void comp_mfma_k(const short* __restrict__ Ubf, const short* __restrict__ Cbf,
                                                   float* __restrict__ partm, float* __restrict__ parts) {
    int tid = threadIdx.x;
    int w = tid >> 6, lane = tid & 63;
    int lrow = lane & 15, lhi = lane >> 4;
    int ubase = blockIdx.x * 128 + w * 32;
    int p = blockIdx.y;

    __shared__ __align__(16) short ct[2][16][136];   // +16B row pad; 8.5 KB

    short8 a[2][4];
#pragma unroll
    for (int s2 = 0; s2 < 2; ++s2)
#pragma unroll
        for (int kc = 0; kc < 4; ++kc)
            a[s2][kc] = *(const short8*)(Ubf + (size_t)(ubase + s2 * 16 + lrow) * DD + kc * 32 + lhi * 8);

    float s[2][4];
#pragma unroll
    for (int s2 = 0; s2 < 2; ++s2)
#pragma unroll
        for (int r = 0; r < 4; ++r) s[s2][r] = 0.f;

    int c0 = p * TILES_PP * 16;
    int srow = tid >> 4, scol = (tid & 15) * 8;
    {
        short8 v = *(const short8*)(Cbf + (size_t)(c0 + srow) * DD + scol);
        *(short8*)&ct[0][srow][scol] = v;
    }

    for (int tile = 0; tile < TILES_PP; ++tile) {
        int cur = tile & 1;
        short8 pf;
        bool hn = (tile + 1 < TILES_PP);
        if (hn)
            pf = *(const short8*)(Cbf + (size_t)(c0 + (tile + 1) * 16 + srow) * DD + scol);
        __syncthreads();
        if (hn) *(short8*)&ct[cur ^ 1][srow][scol] = pf;

        f32x4 acc0 = {0.f, 0.f, 0.f, 0.f};
        f32x4 acc1 = {0.f, 0.f, 0.f, 0.f};
#pragma unroll
        for (int kc = 0; kc < 4; ++kc) {
            short8 b = *(const short8*)&ct[cur][lrow][kc * 32 + lhi * 8];
            acc0 = __builtin_amdgcn_mfma_f32_16x16x32_bf16(a[0][kc], b, acc0, 0, 0, 0);
            acc1 = __builtin_amdgcn_mfma_f32_16x16x32_bf16(a[1][kc], b, acc1, 0, 0, 0);
        }
#pragma unroll
        for (int r = 0; r < 4; ++r) {
            s[0][r] += __expf(acc0[r]);
            s[1][r] += __expf(acc1[r]);
        }
    }

#pragma unroll
    for (int s2 = 0; s2 < 2; ++s2)
#pragma unroll
        for (int r = 0; r < 4; ++r) {
            float S = s[s2][r];
#pragma unroll
            for (int o = 1; o < 16; o <<= 1)
                S += __shfl_xor(S, o, 64);
            if (lrow == 0) {
                int u = ubase + s2 * 16 + lhi * 4 + r;
                partm[(size_t)u * PPART + p] = 0.f;
                parts[(size_t)u * PPART + p] = S;
            }
        }
}

// ---------------- finish (wave-per-user) ----------------
__global__ __launch_bounds__(256) void finish2_k(const unsigned char* __restrict__ hfin,
                                                 const float* __restrict__ ent,
                                                 const float* __restrict__ rel, const int* __restrict__ ub,
                                                 const int* __restrict__ ct, const int* __restrict__ jt,
                                                 const float* __restrict__ partm, const float* __restrict__ parts,
                                                 float* __restrict__ out) {
    __shared__ float s_u[4][128];
    int w = threadIdx.x >> 6, lane = threadIdx.x & 63;
    int u = blockIdx.x * 4 + w;

    const unsigned char* up = hfin + (size_t)ub[u] * DD;
    float u0 = fp8_to_f(up[lane]), u1 = fp8_to_f(up[lane + 64]);
    s_u[w][lane] = u0;
    s_u[w][lane + 64] = u1;   // same-wave LDS write->read, no barrier needed

    const float* tcp = ent + (size_t)(USER_NUM_ + ct[u]) * DD;
    float pc = u0 * tcp[lane] + u1 * tcp[lane + 64];
    const float* tjp = rel + (size_t)jt[u] * DD;
    float pj = u0 * tjp[lane] + u1 * tjp[lane + 64];
#pragma unroll
    for (int o = 1; o < 64; o <<= 1) {
        pc += __shfl_xor(pc, o, 64);
        pj += __shfl_xor(pj, o, 64);
    }

    float M = partm[(size_t)u * PPART + lane];
    float S = parts[(size_t)u * PPART + lane];
    if (lane + 64 < PPART)
        lse_merge(M, S, partm[(size_t)u * PPART + lane + 64], parts[(size_t)u * PPART + lane + 64]);
#pragma unroll
    for (int o = 1; o < 64; o <<= 1) {
        float M2 = __shfl_xor(M, o, 64);
        float S2 = __shfl_xor(S, o, 64);
        lse_merge(M, S, M2, S2);
    }
    float lse_c = M + logf(S);

    int j1 = lane, j2 = lane + 64;
    bool v2 = j2 < (REL_NUM_ / 2);
    const float* r1 = rel + (size_t)j1 * DD;
    const float* r2 = rel + (size_t)(v2 ? j2 : 0) * DD;
    float d1 = 0.f, d2 = 0.f;
#pragma unroll 16
    for (int k = 0; k < DD; ++k) {
        float uk = s_u[w][k];
        d1 = fmaf(uk, r1[k], d1);
        d2 = fmaf(uk, r2[k], d2);
    }
    float Mj = d1, Sj = 1.f;
    if (v2) lse_push(d2, Mj, Sj);
#pragma unroll
    for (int o = 1; o < 64; o <<= 1) {
        float M2 = __shfl_xor(Mj, o, 64);
        float S2 = __shfl_xor(Sj, o, 64);
        lse_merge(Mj, Sj, M2, S2);
    }
    float lse_j = Mj + logf(Sj);

    if (lane == 0) {
        atomicAdd(&out[0], lse_c - pc);
        atomicAdd(&out[1], lse_j - pj);
    }
}

// ---------------- host ----------------
static inline size_t rup(size_t x) { return (x + 255) & ~(size_t)255; }

extern "C" void kernel_launch(void* const* d_in, const int* in_sizes, int n_in,
                              void* d_out, int out_size, void* d_ws, size_t ws_size,
                              hipStream_t stream) {
    const float* ent_emb = (const float*)d_in[0];
    const float* c0_emb  = (const float*)d_in[1];
    const float* rel_emb = (const float*)d_in[2];
    const float* W_ih    = (const float*)d_in[3];
    const float* W_hh    = (const float*)d_in[4];
    const float* b_ih    = (const float*)d_in[5];
    const float* b_hh    = (const float*)d_in[6];
    const int* src       = (const int*)d_in[7];
    const int* dst       = (const int*)d_in[8];
    const int* rel_idx   = (const int*)d_in[9];
    const int* seed_idx  = (const int*)d_in[10];
    const int* ubatch    = (const int*)d_in[11];
    const int* ctarg     = (const int*)d_in[12];
    const int* jtarg     = (const int*)d_in[13];
    float* out = (float*)d_out;

    const size_t HB8 = rup((size_t)EN * DD);        // fp8 h buffer: 19,200,256
    const size_t HBH = rup((size_t)EN * DD * 2);    // bf16 c buffer

    char* base = (char*)d_ws;
    unsigned char* h0   = (unsigned char*)base;
    unsigned char* h1   = (unsigned char*)(base + HB8);
    unsigned short* cbuf = (unsigned short*)(base + 2 * HB8);

    int* startp; int* pairs; int2* bucketed; int* bcnt; int* bbase; int* bcur;
    int* seedpos; unsigned char* xh; int* ctrbuf;
    unsigned char* Wt8; float* bsumv; unsigned short* Rbf;
    auto place = [&](int NT) -> size_t {
        size_t o = 2 * HB8 + HBH;
        startp   = (int*)(base + o);  o += rup((size_t)NT * EN * 4);
        pairs    = (int*)(base + o);  o += rup((size_t)NT * EE * 4);
        bucketed = (int2*)(base + o); o += rup((size_t)NT * EE * 8);
        seedpos  = (int*)(base + o);  o += rup((size_t)NT * EN * 4);
        xh       = (unsigned char*)(base + o); o += rup((size_t)SS * XHROW);
        bcnt     = (int*)(base + o);  o += rup((size_t)NT * NB * 4);
        bbase    = (int*)(base + o);  o += rup((size_t)NT * (NB + 1) * 4);
        bcur     = (int*)(base + o);  o += rup((size_t)NT * NB * 4);
        ctrbuf   = (int*)(base + o);  o += rup((size_t)NT * 4);
        Wt8      = (unsigned char*)(base + o); o += rup(512 * 256);
        bsumv    = (float*)(base + o); o += rup(512 * 4);
        Rbf      = (unsigned short*)(base + o); o += rup((size_t)REL_NUM_ * DD * 2);
        return o;
    };

    const int cands[6] = {12, 6, 4, 3, 2, 1};
    int NT = 1;
    for (int i = 0; i < 6; ++i) {
        if (place(cands[i]) <= ws_size) { NT = cands[i]; break; }
    }
    place(NT);  // final pointers

    // comp-phase buffers alias cbuf region (dead after step loop)
    char* q = (char*)cbuf;
    short* Cbf = (short*)q;            q += rup((size_t)COMP_NUM_ * DD * 2);  // 12.8 MB
    short* Ubf = (short*)q;            q += rup((size_t)BB * DD * 2);
    float* partm = (float*)q;          q += rup((size_t)BB * PPART * 4);
    float* parts = (float*)q;

    hipMemsetAsync(d_out, 0, 2 * sizeof(float), stream);

    const int n4 = EN * DD / 4;
    const int gcpy = (n4 + 255) / 256;

    prepW_k<<<512, 256, 0, stream>>>(W_ih, W_hh, b_ih, b_hh, Wt8, bsumv);
    packF8_k<<<gcpy, 256, 0, stream>>>(ent_emb, (unsigned*)h0, n4);
    packBF_k<<<gcpy, 256, 0, stream>>>(c0_emb, (ushort4*)cbuf, n4);
    packBF_k<<<(REL_NUM_ * DD / 4 + 255) / 256, 256, 0, stream>>>(rel_emb, (ushort4*)Rbf, REL_NUM_ * DD / 4);

    auto build = [&](int t0, int nt) {
        zero_i32_k<<<(nt * NB + 255) / 256, 256, 0, stream>>>(bcnt, nt * NB);
        zero_i32_k<<<1, 256, 0, stream>>>(ctrbuf, nt);
        binA_k<<<dim3(NCH, nt), 256, 0, stream>>>(dst, bcnt, t0);
        binScan_k<<<1, 64, 0, stream>>>(bcnt, bbase, bcur, nt);
        binB_k<<<dim3(NCH, nt), 256, 0, stream>>>(src, dst, rel_idx, bcur, bucketed, t0);
        histscat_k<<<dim3(NB, nt), 256, 0, stream>>>(bucketed, bbase, startp, pairs);
        hipMemsetAsync(seedpos, 0xFF, (size_t)nt * EN * 4, stream);
        spos_k<<<dim3((SS + 255) / 256, nt), 256, 0, stream>>>(seed_idx, seedpos, t0);
    };

    unsigned char* hold = h0;
    unsigned char* hnew = h1;

    for (int b0 = 0; b0 < TT; b0 += NT) {
        int nb = (TT - b0 < NT) ? (TT - b0) : NT;
        build(b0, nb);
        for (int k = 0; k < nb; ++k) {
            int t = b0 + k;
            aggstm_k<<<GAGG + GLSTM, 256, 0, stream>>>(hold, hnew, Rbf, cbuf, startp, pairs,
                                                       seedpos, xh, Wt8, bsumv,
                                                       seed_idx + (size_t)t * SS, ctrbuf + k, k);
            unsigned char* tmp = hold; hold = hnew; hnew = tmp;
        }
    }

    // NOTE: cbuf region is reused for Cbf/Ubf/partials from here on
    packBF_k<<<(COMP_NUM_ * DD / 4 + 255) / 256, 256, 0, stream>>>(ent_emb + (size_t)USER_NUM_ * DD,
                                                                   (ushort4*)Cbf, COMP_NUM_ * DD / 4);
    packU_k<<<(BB * DD + 255) / 256, 256, 0, stream>>>(hold, ubatch, Ubf);
    comp_mfma_k<<<dim3(BB / 128, PPART), 256, 0, stream>>>(Ubf, Cbf, partm, parts);
    finish2_k<<<BB / 4, 256, 0, stream>>>(hold, ent_emb, rel_emb, ubatch, ctarg, jtarg,
                                          partm, parts, out);
}

// Round 22
// 848.335 us; speedup vs baseline: 14.6360x; 14.6360x over previous
//
#include <hip/hip_runtime.h>
#include <math.h>

typedef __attribute__((ext_vector_type(8))) short short8;
typedef __attribute__((ext_vector_type(8))) unsigned short u16x8;
typedef __attribute__((ext_vector_type(4))) float f32x4;
typedef __attribute__((ext_vector_type(2))) float f32x2;
typedef long i64;

#define USER_NUM_  100000
#define COMP_NUM_  50000
#define EN         150002
#define REL_NUM_   200
#define DD         128
#define TT         12
#define EE         250000
#define SS         20000
#define BB         1024
#define PPART      125      // comp partitions
#define TILES_PP   25       // 16-comp tiles per partition
#define NB         37       // coarse buckets: dst>>12, 37*4096 >= EN
#define BSH        12
#define CHUNK      4096     // edges per binA/binB block
#define NCH        62       // ceil(EE/CHUNK)

__device__ inline unsigned short f2bf(float f) {
    unsigned u = __float_as_uint(f);
    unsigned r = (u + 0x7fffu + ((u >> 16) & 1u)) >> 16;
    return (unsigned short)r;
}

__device__ inline float bf2f(unsigned short u) {
    return __uint_as_float((unsigned)u << 16);
}

// ---- fp8 e4m3 (OCP) hardware converts ----
__device__ inline void fp8x8_to_f(uint2 u, float f[8]) {
    f32x2 a = __builtin_amdgcn_cvt_pk_f32_fp8((int)u.x, false);
    f32x2 b = __builtin_amdgcn_cvt_pk_f32_fp8((int)u.x, true);
    f32x2 c = __builtin_amdgcn_cvt_pk_f32_fp8((int)u.y, false);
    f32x2 d = __builtin_amdgcn_cvt_pk_f32_fp8((int)u.y, true);
    f[0] = a[0]; f[1] = a[1]; f[2] = b[0]; f[3] = b[1];
    f[4] = c[0]; f[5] = c[1]; f[6] = d[0]; f[7] = d[1];
}

__device__ inline unsigned fp8x4_pack(float f0, float f1, float f2, float f3) {
    int v = __builtin_amdgcn_cvt_pk_fp8_f32(f0, f1, 0, false);
    v = __builtin_amdgcn_cvt_pk_fp8_f32(f2, f3, v, true);
    return (unsigned)v;
}

__device__ inline unsigned char f_to_fp8(float f) {
    return (unsigned char)(__builtin_amdgcn_cvt_pk_fp8_f32(f, f, 0, false) & 0xff);
}

__device__ inline float fp8_to_f(unsigned char b) {
    return __builtin_amdgcn_cvt_f32_fp8((int)b, 0);
}

__device__ inline float sigmoidf_(float x) { return 1.f / (1.f + __expf(-x)); }

__device__ inline void lse_push(float v, float& m, float& s) {
    if (v <= m) { s += __expf(v - m); }
    else { s = s * __expf(m - v) + 1.f; m = v; }
}

__device__ inline void lse_merge(float& M, float& S, float M2, float S2) {
    float Mn = fmaxf(M, M2);
    S = S * __expf(M - Mn) + S2 * __expf(M2 - Mn);
    M = Mn;
}

// ---------------- utility ----------------
__global__ __launch_bounds__(256) void packBF_k(const float* __restrict__ src, ushort4* __restrict__ dst, int n4) {
    int i = blockIdx.x * 256 + threadIdx.x;
    if (i >= n4) return;
    float4 v = ((const float4*)src)[i];
    ushort4 o;
    o.x = f2bf(v.x); o.y = f2bf(v.y); o.z = f2bf(v.z); o.w = f2bf(v.w);
    dst[i] = o;
}

__global__ __launch_bounds__(256) void packF8_k(const float* __restrict__ src, unsigned* __restrict__ dst, int n4) {
    int i = blockIdx.x * 256 + threadIdx.x;
    if (i >= n4) return;
    float4 v = ((const float4*)src)[i];
    dst[i] = fp8x4_pack(v.x, v.y, v.z, v.w);
}

__global__ __launch_bounds__(256) void zero_i32_k(int* __restrict__ p, int n) {
    int i = blockIdx.x * 256 + threadIdx.x;
    if (i < n) p[i] = 0;
}

// W packed to fp8: Wt8[n][k], n=gate unit (512), k=0..255 ([xi|hp] order)
__global__ __launch_bounds__(256) void prepW_k(const float* __restrict__ Wih, const float* __restrict__ Whh,
                                               const float* __restrict__ bih, const float* __restrict__ bhh,
                                               unsigned char* __restrict__ Wt8, float* __restrict__ bsum) {
    int n = blockIdx.x;      // 0..511
    int k = threadIdx.x;     // 0..255
    float v = (k < 128) ? Wih[n * 128 + k] : Whh[n * 128 + (k - 128)];
    Wt8[n * 256 + k] = f_to_fp8(v);
    if (k == 0) bsum[n] = bih[n] + bhh[n];
}

// ---------------- two-level binned CSR build ----------------
__global__ __launch_bounds__(256) void binA_k(const int* __restrict__ dst, int* __restrict__ bcnt,
                                              int t0) {
    int slot = blockIdx.y;
    int tid = threadIdx.x;
    int c0 = blockIdx.x * CHUNK;
    int w = tid >> 6;
    __shared__ int lcnt[4][NB];
    for (int i = tid; i < 4 * NB; i += 256) ((int*)lcnt)[i] = 0;
    __syncthreads();
#pragma unroll
    for (int i = 0; i < 16; ++i) {
        int e = c0 + i * 256 + tid;
        if (e < EE) {
            int d = __builtin_nontemporal_load(&dst[(size_t)(t0 + slot) * EE + e]);
            atomicAdd(&lcnt[w][d >> BSH], 1);
        }
    }
    __syncthreads();
    if (tid < NB)
        atomicAdd(&bcnt[slot * NB + tid], lcnt[0][tid] + lcnt[1][tid] + lcnt[2][tid] + lcnt[3][tid]);
}

__global__ __launch_bounds__(64) void binScan_k(const int* __restrict__ bcnt, int* __restrict__ bbase,
                                                int* __restrict__ bcur, int nt) {
    int slot = threadIdx.x;
    if (slot >= nt) return;
    int b = 0;
    for (int c = 0; c < NB; ++c) {
        bbase[slot * (NB + 1) + c] = b;
        bcur[slot * NB + c] = b;
        b += bcnt[slot * NB + c];
    }
    bbase[slot * (NB + 1) + NB] = b;   // == EE
}

__global__ __launch_bounds__(256) void binB_k(const int* __restrict__ src, const int* __restrict__ dst,
                                              const int* __restrict__ rel, int* __restrict__ bcur,
                                              int2* __restrict__ bucketed, int t0) {
    int slot = blockIdx.y;
    int tid = threadIdx.x;
    int c0 = blockIdx.x * CHUNK;
    __shared__ int lcnt[NB], lbase[NB], gbase[NB], lcur[NB];
    __shared__ int2 stage[CHUNK];   // 32 KB
    if (tid < NB) lcnt[tid] = 0;
    __syncthreads();

    int myb[16]; int2 myv[16];
#pragma unroll
    for (int i = 0; i < 16; ++i) {
        int e = c0 + i * 256 + tid;
        if (e < EE) {
            size_t gi = (size_t)(t0 + slot) * EE + e;
            int d = __builtin_nontemporal_load(&dst[gi]);
            int s = __builtin_nontemporal_load(&src[gi]);
            int r = __builtin_nontemporal_load(&rel[gi]);
            myb[i] = d >> BSH;
            myv[i] = make_int2(d, s | (r << 18));
            atomicAdd(&lcnt[myb[i]], 1);
        } else myb[i] = -1;
    }
    __syncthreads();
    if (tid == 0) {
        int b = 0;
        for (int c = 0; c < NB; ++c) { lbase[c] = b; b += lcnt[c]; }
    }
    __syncthreads();
    if (tid < NB) {
        gbase[tid] = (lcnt[tid] > 0) ? atomicAdd(&bcur[slot * NB + tid], lcnt[tid]) : 0;
        lcur[tid] = lbase[tid];
    }
    __syncthreads();
#pragma unroll
    for (int i = 0; i < 16; ++i) {
        if (myb[i] >= 0) {
            int p = atomicAdd(&lcur[myb[i]], 1);
            stage[p] = myv[i];
        }
    }
    __syncthreads();
    int w = tid >> 6, lane = tid & 63;
    int2* bout = bucketed + (size_t)slot * EE;
    for (int b = w; b < NB; b += 4) {
        int cnt = lcnt[b], lb = lbase[b], gb = gbase[b];
        for (int j = lane; j < cnt; j += 64)
            bout[gb + j] = stage[lb + j];
    }
}

// per-(slot,bucket): fused histogram + in-LDS scan + scatter + end-offset writeback.
__global__ __launch_bounds__(256) void histscat_k(const int2* __restrict__ bucketed,
                                                  const int* __restrict__ bbase,
                                                  int* __restrict__ startp, int* __restrict__ pairs) {
    int b = blockIdx.x, slot = blockIdx.y;
    int tid = threadIdx.x;
    int base_ent = b << BSH;
    int nloc = EN - base_ent; if (nloc > 4096) nloc = 4096;
    __shared__ int lcnt[4096];
    __shared__ int tsum[256];
    for (int i = tid; i < 4096; i += 256) lcnt[i] = 0;
    __syncthreads();
    int e0 = bbase[slot * (NB + 1) + b], e1 = bbase[slot * (NB + 1) + b + 1];
    const int2* bin = bucketed + (size_t)slot * EE;
    for (int e = e0 + tid; e < e1; e += 256)
        atomicAdd(&lcnt[bin[e].x - base_ent], 1);
    __syncthreads();
    int base16 = tid * 16;
    int s = 0;
#pragma unroll
    for (int k = 0; k < 16; ++k) s += lcnt[base16 + k];
    tsum[tid] = s;
    __syncthreads();
#pragma unroll
    for (int o = 1; o < 256; o <<= 1) {
        int x = (tid >= o) ? tsum[tid - o] : 0;
        __syncthreads();
        tsum[tid] += x;
        __syncthreads();
    }
    int run = e0 + tsum[tid] - s;
#pragma unroll
    for (int k = 0; k < 16; ++k) {
        int c = lcnt[base16 + k];
        lcnt[base16 + k] = run;
        run += c;
    }
    __syncthreads();
    int* pout = pairs + (size_t)slot * EE;
    for (int e = e0 + tid; e < e1; e += 256) {
        int2 ed = bin[e];
        int pos = atomicAdd(&lcnt[ed.x - base_ent], 1);
        pout[pos] = ed.y;
    }
    __syncthreads();
    for (int i = tid; i < nloc; i += 256)
        startp[(size_t)slot * EN + base_ent + i] = lcnt[i];   // end offsets
}

// ---------------- fused aggregate: x[d] = h[d] + (1/cnt)*sum h[src]*rel[r] (fp8 h) -----
__global__ __launch_bounds__(256) void agg_k(const unsigned char* __restrict__ hold,
                                             unsigned char* __restrict__ hnew,
                                             const unsigned short* __restrict__ Rbf,
                                             const int* __restrict__ endp_all,
                                             const int* __restrict__ pairs, int slot) {
    int tid = threadIdx.x;
    int d = blockIdx.x * 16 + (tid >> 4);
    int l = tid & 15;
    if (d >= EN) return;
    const int* endp = endp_all + (size_t)slot * EN;
    int e0 = (d > 0) ? endp[d - 1] : 0;
    int e1 = endp[d];
    const int* pp = pairs + (size_t)slot * EE;
    float acc[8];
#pragma unroll
    for (int j = 0; j < 8; ++j) acc[j] = 0.f;
    int e = e0;
    for (; e + 2 <= e1; e += 2) {
        int pk0 = pp[e], pk1 = pp[e + 1];
        uint2 h0 = *(const uint2*)(hold + (size_t)(pk0 & 0x3FFFF) * DD + l * 8);
        u16x8 r0 = *(const u16x8*)(Rbf + (size_t)(pk0 >> 18) * DD + l * 8);
        uint2 h1 = *(const uint2*)(hold + (size_t)(pk1 & 0x3FFFF) * DD + l * 8);
        u16x8 r1 = *(const u16x8*)(Rbf + (size_t)(pk1 >> 18) * DD + l * 8);
        float hf0[8], hf1[8];
        fp8x8_to_f(h0, hf0);
        fp8x8_to_f(h1, hf1);
#pragma unroll
        for (int j = 0; j < 8; ++j)
            acc[j] = fmaf(hf1[j], bf2f(r1[j]), fmaf(hf0[j], bf2f(r0[j]), acc[j]));
    }
    if (e < e1) {
        int pk0 = pp[e];
        uint2 h0 = *(const uint2*)(hold + (size_t)(pk0 & 0x3FFFF) * DD + l * 8);
        u16x8 r0 = *(const u16x8*)(Rbf + (size_t)(pk0 >> 18) * DD + l * 8);
        float hf0[8];
        fp8x8_to_f(h0, hf0);
#pragma unroll
        for (int j = 0; j < 8; ++j)
            acc[j] = fmaf(hf0[j], bf2f(r0[j]), acc[j]);
    }
    uint2 hd = *(const uint2*)(hold + (size_t)d * DD + l * 8);
    float hdf[8];
    fp8x8_to_f(hd, hdf);
    int c = e1 - e0;
    float inv = (c > 0) ? 1.f / (float)c : 0.f;
    float o[8];
#pragma unroll
    for (int j = 0; j < 8; ++j) o[j] = fmaf(acc[j], inv, hdf[j]);
    uint2 ov;
    ov.x = fp8x4_pack(o[0], o[1], o[2], o[3]);
    ov.y = fp8x4_pack(o[4], o[5], o[6], o[7]);
    *(uint2*)(hnew + (size_t)d * DD + l * 8) = ov;
}

// ---------------- LSTM on seed rows: native fp8 MFMA (A=rows, B=Wt8) ----------------
// gates = [xi|hp] @ W^T via mfma_f32_16x16x32_fp8_fp8; A/B frags are 8 fp8 bytes (i64).
__global__ __launch_bounds__(256) void lstm_k(const unsigned char* __restrict__ hold,
                                              unsigned char* __restrict__ hnew,
                                              unsigned short* __restrict__ cbuf,
                                              const unsigned char* __restrict__ Wt8,
                                              const float* __restrict__ bsum, const int* __restrict__ seed) {
    int w = threadIdx.x >> 6;
    int lane = threadIdx.x & 63;
    int lrow = lane & 15, lhi = lane >> 4;
    int m0 = blockIdx.x * 32;
    int w32 = w * 32;

    const unsigned char* pxi[2];
    const unsigned char* php[2];
#pragma unroll
    for (int mi = 0; mi < 2; ++mi) {
        int m = m0 + mi * 16 + lrow;
        int sd = seed[m];
        pxi[mi] = hnew + (size_t)sd * DD;
        php[mi] = hold + (size_t)sd * DD;
    }

    f32x4 acc[2][4][2];
#pragma unroll
    for (int mi = 0; mi < 2; ++mi)
#pragma unroll
        for (int g = 0; g < 4; ++g)
#pragma unroll
            for (int s = 0; s < 2; ++s)
                acc[mi][g][s] = (f32x4){0.f, 0.f, 0.f, 0.f};

#pragma unroll
    for (int kk = 0; kk < 8; ++kk) {
        int klane = kk * 32 + lhi * 8;
        i64 af[2];
#pragma unroll
        for (int mi = 0; mi < 2; ++mi) {
            const unsigned char* p = (klane < 128) ? (pxi[mi] + klane) : (php[mi] + (klane - 128));
            af[mi] = *(const i64*)p;
        }
#pragma unroll
        for (int g = 0; g < 4; ++g)
#pragma unroll
            for (int s = 0; s < 2; ++s) {
                int col = g * 128 + w32 + s * 16 + lrow;
                i64 bf = *(const i64*)(Wt8 + (size_t)col * 256 + klane);
                acc[0][g][s] = __builtin_amdgcn_mfma_f32_16x16x32_fp8_fp8(af[0], bf, acc[0][g][s], 0, 0, 0);
                acc[1][g][s] = __builtin_amdgcn_mfma_f32_16x16x32_fp8_fp8(af[1], bf, acc[1][g][s], 0, 0, 0);
            }
    }

    __syncthreads();  // all xi reads done before seed rows are overwritten

#pragma unroll
    for (int mi = 0; mi < 2; ++mi) {
#pragma unroll
        for (int r = 0; r < 4; ++r) {
            int m = m0 + mi * 16 + lhi * 4 + r;
            int sd = seed[m];
#pragma unroll
            for (int s = 0; s < 2; ++s) {
                int d = w32 + s * 16 + lrow;
                float ig = acc[mi][0][s][r] + bsum[d];
                float fg = acc[mi][1][s][r] + bsum[128 + d];
                float gg = acc[mi][2][s][r] + bsum[256 + d];
                float og = acc[mi][3][s][r] + bsum[384 + d];
                float cp = bf2f(cbuf[(size_t)sd * DD + d]);
                float cn = sigmoidf_(fg) * cp + sigmoidf_(ig) * tanhf(gg);
                float hn = sigmoidf_(og) * tanhf(cn);
                cbuf[(size_t)sd * DD + d] = f2bf(cn);
                hnew[(size_t)sd * DD + d] = f_to_fp8(hn);
            }
        }
    }
}

// ---------------- comp loss: pack u rows (fp8 -> bf16) ----------------
__global__ __launch_bounds__(256) void packU_k(const unsigned char* __restrict__ hfin, const int* __restrict__ ub,
                                               short* __restrict__ Ubf) {
    int i = blockIdx.x * 256 + threadIdx.x;    // over 1024*128
    if (i >= BB * DD) return;
    int u = i >> 7, k = i & 127;
    Ubf[i] = (short)f2bf(fp8_to_f(hfin[(size_t)ub[u] * DD + k]));
}

// ---------------- comp loss: MFMA GEMM, LDS-staged tiles, no-max exp-sum ----------------
__global__ __launch_bounds__(256) void comp_mfma_k(const short* __restrict__ Ubf, const short* __restrict__ Cbf,
                                                   float* __restrict__ partm, float* __restrict__ parts) {
    int tid = threadIdx.x;
    int w = tid >> 6, lane = tid & 63;
    int lrow = lane & 15, lhi = lane >> 4;
    int ubase = blockIdx.x * 128 + w * 32;
    int p = blockIdx.y;

    __shared__ __align__(16) short ct[2][16][136];   // +16B row pad; 8.5 KB

    short8 a[2][4];
#pragma unroll
    for (int s2 = 0; s2 < 2; ++s2)
#pragma unroll
        for (int kc = 0; kc < 4; ++kc)
            a[s2][kc] = *(const short8*)(Ubf + (size_t)(ubase + s2 * 16 + lrow) * DD + kc * 32 + lhi * 8);

    float s[2][4];
#pragma unroll
    for (int s2 = 0; s2 < 2; ++s2)
#pragma unroll
        for (int r = 0; r < 4; ++r) s[s2][r] = 0.f;

    int c0 = p * TILES_PP * 16;
    int srow = tid >> 4, scol = (tid & 15) * 8;
    {
        short8 v = *(const short8*)(Cbf + (size_t)(c0 + srow) * DD + scol);
        *(short8*)&ct[0][srow][scol] = v;
    }

    for (int tile = 0; tile < TILES_PP; ++tile) {
        int cur = tile & 1;
        short8 pf;
        bool hn = (tile + 1 < TILES_PP);
        if (hn)
            pf = *(const short8*)(Cbf + (size_t)(c0 + (tile + 1) * 16 + srow) * DD + scol);
        __syncthreads();
        if (hn) *(short8*)&ct[cur ^ 1][srow][scol] = pf;

        f32x4 acc0 = {0.f, 0.f, 0.f, 0.f};
        f32x4 acc1 = {0.f, 0.f, 0.f, 0.f};
#pragma unroll
        for (int kc = 0; kc < 4; ++kc) {
            short8 b = *(const short8*)&ct[cur][lrow][kc * 32 + lhi * 8];
            acc0 = __builtin_amdgcn_mfma_f32_16x16x32_bf16(a[0][kc], b, acc0, 0, 0, 0);
            acc1 = __builtin_amdgcn_mfma_f32_16x16x32_bf16(a[1][kc], b, acc1, 0, 0, 0);
        }
#pragma unroll
        for (int r = 0; r < 4; ++r) {
            s[0][r] += __expf(acc0[r]);
            s[1][r] += __expf(acc1[r]);
        }
    }

#pragma unroll
    for (int s2 = 0; s2 < 2; ++s2)
#pragma unroll
        for (int r = 0; r < 4; ++r) {
            float S = s[s2][r];
#pragma unroll
            for (int o = 1; o < 16; o <<= 1)
                S += __shfl_xor(S, o, 64);
            if (lrow == 0) {
                int u = ubase + s2 * 16 + lhi * 4 + r;
                partm[(size_t)u * PPART + p] = 0.f;
                parts[(size_t)u * PPART + p] = S;
            }
        }
}

// ---------------- finish (wave-per-user) ----------------
__global__ __launch_bounds__(256) void finish2_k(const unsigned char* __restrict__ hfin,
                                                 const float* __restrict__ ent,
                                                 const float* __restrict__ rel, const int* __restrict__ ub,
                                                 const int* __restrict__ ct, const int* __restrict__ jt,
                                                 const float* __restrict__ partm, const float* __restrict__ parts,
                                                 float* __restrict__ out) {
    __shared__ float s_u[4][128];
    int w = threadIdx.x >> 6, lane = threadIdx.x & 63;
    int u = blockIdx.x * 4 + w;

    const unsigned char* up = hfin + (size_t)ub[u] * DD;
    float u0 = fp8_to_f(up[lane]), u1 = fp8_to_f(up[lane + 64]);
    s_u[w][lane] = u0;
    s_u[w][lane + 64] = u1;   // same-wave LDS write->read, no barrier needed

    const float* tcp = ent + (size_t)(USER_NUM_ + ct[u]) * DD;
    float pc = u0 * tcp[lane] + u1 * tcp[lane + 64];
    const float* tjp = rel + (size_t)jt[u] * DD;
    float pj = u0 * tjp[lane] + u1 * tjp[lane + 64];
#pragma unroll
    for (int o = 1; o < 64; o <<= 1) {
        pc += __shfl_xor(pc, o, 64);
        pj += __shfl_xor(pj, o, 64);
    }

    float M = partm[(size_t)u * PPART + lane];
    float S = parts[(size_t)u * PPART + lane];
    if (lane + 64 < PPART)
        lse_merge(M, S, partm[(size_t)u * PPART + lane + 64], parts[(size_t)u * PPART + lane + 64]);
#pragma unroll
    for (int o = 1; o < 64; o <<= 1) {
        float M2 = __shfl_xor(M, o, 64);
        float S2 = __shfl_xor(S, o, 64);
        lse_merge(M, S, M2, S2);
    }
    float lse_c = M + logf(S);

    int j1 = lane, j2 = lane + 64;
    bool v2 = j2 < (REL_NUM_ / 2);
    const float* r1 = rel + (size_t)j1 * DD;
    const float* r2 = rel + (size_t)(v2 ? j2 : 0) * DD;
    float d1 = 0.f, d2 = 0.f;
#pragma unroll 16
    for (int k = 0; k < DD; ++k) {
        float uk = s_u[w][k];
        d1 = fmaf(uk, r1[k], d1);
        d2 = fmaf(uk, r2[k], d2);
    }
    float Mj = d1, Sj = 1.f;
    if (v2) lse_push(d2, Mj, Sj);
#pragma unroll
    for (int o = 1; o < 64; o <<= 1) {
        float M2 = __shfl_xor(Mj, o, 64);
        float S2 = __shfl_xor(Sj, o, 64);
        lse_merge(Mj, Sj, M2, S2);
    }
    float lse_j = Mj + logf(Sj);

    if (lane == 0) {
        atomicAdd(&out[0], lse_c - pc);
        atomicAdd(&out[1], lse_j - pj);
    }
}

// ---------------- host ----------------
static inline size_t rup(size_t x) { return (x + 255) & ~(size_t)255; }

extern "C" void kernel_launch(void* const* d_in, const int* in_sizes, int n_in,
                              void* d_out, int out_size, void* d_ws, size_t ws_size,
                              hipStream_t stream) {
    const float* ent_emb = (const float*)d_in[0];
    const float* c0_emb  = (const float*)d_in[1];
    const float* rel_emb = (const float*)d_in[2];
    const float* W_ih    = (const float*)d_in[3];
    const float* W_hh    = (const float*)d_in[4];
    const float* b_ih    = (const float*)d_in[5];
    const float* b_hh    = (const float*)d_in[6];
    const int* src       = (const int*)d_in[7];
    const int* dst       = (const int*)d_in[8];
    const int* rel_idx   = (const int*)d_in[9];
    const int* seed_idx  = (const int*)d_in[10];
    const int* ubatch    = (const int*)d_in[11];
    const int* ctarg     = (const int*)d_in[12];
    const int* jtarg     = (const int*)d_in[13];
    float* out = (float*)d_out;

    const size_t HB8 = rup((size_t)EN * DD);        // fp8 h buffer: 19,200,256
    const size_t HBH = rup((size_t)EN * DD * 2);    // bf16 c buffer

    char* base = (char*)d_ws;
    unsigned char* h0   = (unsigned char*)base;
    unsigned char* h1   = (unsigned char*)(base + HB8);
    unsigned short* cbuf = (unsigned short*)(base + 2 * HB8);

    int* startp; int* pairs; int2* bucketed; int* bcnt; int* bbase; int* bcur;
    unsigned char* Wt8; float* bsumv; unsigned short* Rbf;
    auto place = [&](int NT) -> size_t {
        size_t o = 2 * HB8 + HBH;
        startp   = (int*)(base + o);  o += rup((size_t)NT * EN * 4);
        pairs    = (int*)(base + o);  o += rup((size_t)NT * EE * 4);
        bucketed = (int2*)(base + o); o += rup((size_t)NT * EE * 8);
        bcnt     = (int*)(base + o);  o += rup((size_t)NT * NB * 4);
        bbase    = (int*)(base + o);  o += rup((size_t)NT * (NB + 1) * 4);
        bcur     = (int*)(base + o);  o += rup((size_t)NT * NB * 4);
        Wt8      = (unsigned char*)(base + o); o += rup(512 * 256);
        bsumv    = (float*)(base + o); o += rup(512 * 4);
        Rbf      = (unsigned short*)(base + o); o += rup((size_t)REL_NUM_ * DD * 2);
        return o;
    };

    const int cands[6] = {12, 6, 4, 3, 2, 1};
    int NT = 1;
    for (int i = 0; i < 6; ++i) {
        if (place(cands[i]) <= ws_size) { NT = cands[i]; break; }
    }
    place(NT);  // final pointers

    // comp-phase buffers alias cbuf region (dead after step loop)
    char* q = (char*)cbuf;
    short* Cbf = (short*)q;            q += rup((size_t)COMP_NUM_ * DD * 2);  // 12.8 MB
    short* Ubf = (short*)q;            q += rup((size_t)BB * DD * 2);
    float* partm = (float*)q;          q += rup((size_t)BB * PPART * 4);
    float* parts = (float*)q;

    hipMemsetAsync(d_out, 0, 2 * sizeof(float), stream);

    const int n4 = EN * DD / 4;
    const int gcpy = (n4 + 255) / 256;

    prepW_k<<<512, 256, 0, stream>>>(W_ih, W_hh, b_ih, b_hh, Wt8, bsumv);
    packF8_k<<<gcpy, 256, 0, stream>>>(ent_emb, (unsigned*)h0, n4);
    packBF_k<<<gcpy, 256, 0, stream>>>(c0_emb, (ushort4*)cbuf, n4);
    packBF_k<<<(REL_NUM_ * DD / 4 + 255) / 256, 256, 0, stream>>>(rel_emb, (ushort4*)Rbf, REL_NUM_ * DD / 4);

    auto build = [&](int t0, int nt) {
        zero_i32_k<<<(nt * NB + 255) / 256, 256, 0, stream>>>(bcnt, nt * NB);
        binA_k<<<dim3(NCH, nt), 256, 0, stream>>>(dst, bcnt, t0);
        binScan_k<<<1, 64, 0, stream>>>(bcnt, bbase, bcur, nt);
        binB_k<<<dim3(NCH, nt), 256, 0, stream>>>(src, dst, rel_idx, bcur, bucketed, t0);
        histscat_k<<<dim3(NB, nt), 256, 0, stream>>>(bucketed, bbase, startp, pairs);
    };

    unsigned char* hold = h0;
    unsigned char* hnew = h1;
    const int gagg = (EN + 15) / 16;

    for (int b0 = 0; b0 < TT; b0 += NT) {
        int nb = (TT - b0 < NT) ? (TT - b0) : NT;
        build(b0, nb);
        for (int k = 0; k < nb; ++k) {
            int t = b0 + k;
            agg_k<<<gagg, 256, 0, stream>>>(hold, hnew, Rbf, startp, pairs, k);
            lstm_k<<<SS / 32, 256, 0, stream>>>(hold, hnew, cbuf, Wt8, bsumv, seed_idx + (size_t)t * SS);
            unsigned char* tmp = hold; hold = hnew; hnew = tmp;
        }
    }

    // NOTE: cbuf region is reused for Cbf/Ubf/partials from here on
    packBF_k<<<(COMP_NUM_ * DD / 4 + 255) / 256, 256, 0, stream>>>(ent_emb + (size_t)USER_NUM_ * DD,
                                                                   (ushort4*)Cbf, COMP_NUM_ * DD / 4);
    packU_k<<<(BB * DD + 255) / 256, 256, 0, stream>>>(hold, ubatch, Ubf);
    comp_mfma_k<<<dim3(BB / 128, PPART), 256, 0, stream>>>(Ubf, Cbf, partm, parts);
    finish2_k<<<BB / 4, 256, 0, stream>>>(hold, ent_emb, rel_emb, ubatch, ctarg, jtarg,
                                          partm, parts, out);
}